// Round 1
// baseline (1032.292 us; speedup 1.0000x reference)
//
#include <hip/hip_runtime.h>
#include <hip/hip_bf16.h>

// Problem constants
#define PB 4
#define PN 2048
#define PD 1024
#define PH 16
#define PHD 64
#define NSC 11

typedef __attribute__((ext_vector_type(8))) short short8;
typedef __attribute__((ext_vector_type(4))) float floatx4;

// ---------------- cast kernel ----------------
__global__ void cast_f32_to_bf16(const float* __restrict__ in,
                                 __hip_bfloat16* __restrict__ out, int n) {
    int i = blockIdx.x * blockDim.x + threadIdx.x;
    if (i < n) out[i] = __float2bfloat16(in[i]);
}

// ---------------- GEMM: C = A @ B^T (+bias, epilogue) ----------------
// A: [M,K] bf16 row-major; Bm: [Nn,K] bf16 row-major (i.e. W[out][in]).
// EPI 0: out fp32 = acc + bias[col]
// EPI 1: out bf16 = bf16(extra[row,col] * sigmoid(acc + bias[col]))
#define BM 64
#define BN 64
#define BK 32
#define SKP 40  // padded LDS row stride in bf16 elements (80B)

template <int EPI>
__global__ __launch_bounds__(256) void gemm_bt(
    const __hip_bfloat16* __restrict__ A,
    const __hip_bfloat16* __restrict__ Bm,
    const float* __restrict__ bias,
    const float* __restrict__ extra,
    void* __restrict__ outp,
    int M, int Nn, int K) {
    __shared__ alignas(16) __hip_bfloat16 sA[BM * SKP];
    __shared__ alignas(16) __hip_bfloat16 sB[BN * SKP];

    const int tid = threadIdx.x;
    const int lane = tid & 63;
    const int wave = tid >> 6;       // 0..3
    const int wy = wave >> 1;        // 0..1
    const int wx = wave & 1;         // 0..1

    const int ld_row = tid >> 2;         // 0..63
    const int ld_k = (tid & 3) * 8;      // 0,8,16,24

    const int rowA = blockIdx.y * BM + ld_row;
    const int rowB = blockIdx.x * BN + ld_row;

    floatx4 acc[2][2];
#pragma unroll
    for (int i = 0; i < 2; i++)
#pragma unroll
        for (int j = 0; j < 2; j++) acc[i][j] = (floatx4){0.f, 0.f, 0.f, 0.f};

    const int qd = lane >> 4;   // 0..3
    const int r16 = lane & 15;  // 0..15

    for (int k0 = 0; k0 < K; k0 += BK) {
        uint4 va = *(const uint4*)(A + (size_t)rowA * K + k0 + ld_k);
        uint4 vb = *(const uint4*)(Bm + (size_t)rowB * K + k0 + ld_k);
        __syncthreads();
        *(uint4*)(sA + ld_row * SKP + ld_k) = va;
        *(uint4*)(sB + ld_row * SKP + ld_k) = vb;
        __syncthreads();

        short8 af[2], bf[2];
#pragma unroll
        for (int i = 0; i < 2; i++) {
            af[i] = *(const short8*)(sA + (wy * 32 + i * 16 + r16) * SKP + qd * 8);
            bf[i] = *(const short8*)(sB + (wx * 32 + i * 16 + r16) * SKP + qd * 8);
        }
#pragma unroll
        for (int i = 0; i < 2; i++)
#pragma unroll
            for (int j = 0; j < 2; j++)
                acc[i][j] = __builtin_amdgcn_mfma_f32_16x16x32_bf16(
                    af[i], bf[j], acc[i][j], 0, 0, 0);
    }

#pragma unroll
    for (int i = 0; i < 2; i++) {
#pragma unroll
        for (int j = 0; j < 2; j++) {
#pragma unroll
            for (int e = 0; e < 4; e++) {
                int row = blockIdx.y * BM + wy * 32 + i * 16 + qd * 4 + e;
                int col = blockIdx.x * BN + wx * 32 + j * 16 + r16;
                float v = acc[i][j][e] + bias[col];
                if (EPI == 0) {
                    ((float*)outp)[(size_t)row * Nn + col] = v;
                } else {
                    float g = 1.f / (1.f + expf(-v));
                    float a = extra[(size_t)row * Nn + col];
                    ((__hip_bfloat16*)outp)[(size_t)row * Nn + col] =
                        __float2bfloat16(a * g);
                }
            }
        }
    }
}

// ---------------- attention kernel ----------------
// qkv: [B, N, 3D] fp32 (q | k | v chunks of D)
// att: [B, N, D] fp32 (head-gathered output)
__global__ __launch_bounds__(256) void attn_kernel(
    const float* __restrict__ qkv,
    const float* __restrict__ scale_gain,       // [11,16]
    const float* __restrict__ W_qscale,         // [11,64]
    const float* __restrict__ identity_bypass,  // [16]
    const float* __restrict__ pos_bias,         // [44,16]
    float* __restrict__ att) {
    const int wid = blockIdx.x * 4 + (threadIdx.x >> 6);
    const int lane = threadIdx.x & 63;
    const int n = wid & (PN - 1);
    const int h = (wid >> 11) & (PH - 1);
    const int b = wid >> 15;

    const size_t rowbase = ((size_t)b * PN + n) * (3 * PD);
    const int hc = h * PHD + lane;

    float q_l = qkv[rowbase + hc];
    float k0_l = qkv[rowbase + PD + hc];
    float v0_l = qkv[rowbase + 2 * PD + hc];

    auto wsum = [](float v) {
#pragma unroll
        for (int o = 32; o > 0; o >>= 1) v += __shfl_xor(v, o);
        return v;
    };

    float dot0 = wsum(q_l * k0_l);

    // gains = softmax(q @ W_qscale^T + scale_gain[:,h]) over 11 scales
    float e[NSC];
    float mx = -1e30f;
#pragma unroll
    for (int s = 0; s < NSC; s++) {
        float d = wsum(q_l * W_qscale[s * PHD + lane]);
        e[s] = d + scale_gain[s * PH + h];
        mx = fmaxf(mx, e[s]);
    }
    float ssum = 0.f;
#pragma unroll
    for (int s = 0; s < NSC; s++) {
        e[s] = expf(e[s] - mx);
        ssum += e[s];
    }
    const float inv = 1.f / ssum;

    const float D4c[4] = {0.4829629131445341f, 0.8365163037378079f,
                          0.2241438680420134f, -0.1294095225512604f};

    float out_l = 0.f, z = 0.f;
#pragma unroll
    for (int j = 0; j < NSC; j++) {
        const int d = 1 << j;
        const float g = e[j] * inv;
#pragma unroll
        for (int tau = 0; tau < 4; tau++) {
            const int off = d * tau;
            if (off != 0 && off >= PN) continue;  // j=10, tau>=2 skipped
            const float biasv = pos_bias[(j * 4 + tau) * PH + h];
            const float coef = D4c[tau];
            float dotv, v_l;
            if (off == 0) {
                dotv = dot0;
                v_l = v0_l;
            } else if (n >= off) {
                const size_t rb = ((size_t)b * PN + (n - off)) * (3 * PD);
                float k_l = qkv[rb + PD + hc];
                v_l = qkv[rb + 2 * PD + hc];
                dotv = wsum(q_l * k_l);
            } else {
                dotv = 0.f;  // padded zeros: dot = 0, but feat still counts in z
                v_l = 0.f;
            }
            float xx = dotv + biasv;
            float feat = (xx > 0.f ? xx : expf(xx) - 1.f) + 1.f;
            out_l += g * coef * feat * v_l;
            z += g * fabsf(coef) * feat;
        }
    }

    // identity bypass
    float bp = log1pf(expf(identity_bypass[h]));  // softplus
    float f0 = (dot0 > 0.f ? dot0 : expf(dot0) - 1.f) + 1.f;
    out_l += bp * f0 * v0_l;
    z += bp * f0;

    att[((size_t)b * PN + n) * PD + hc] = out_l / (z + 1e-6f);
}

// ---------------- launch ----------------
extern "C" void kernel_launch(void* const* d_in, const int* in_sizes, int n_in,
                              void* d_out, int out_size, void* d_ws, size_t ws_size,
                              hipStream_t stream) {
    const float* x = (const float*)d_in[0];
    const float* W_qkv = (const float*)d_in[1];
    const float* b_qkv = (const float*)d_in[2];
    const float* W_out = (const float*)d_in[3];
    const float* b_out = (const float*)d_in[4];
    const float* W_gate = (const float*)d_in[5];
    const float* b_gate = (const float*)d_in[6];
    const float* scale_gain = (const float*)d_in[7];
    const float* W_qscale = (const float*)d_in[8];
    const float* identity_bypass = (const float*)d_in[9];
    const float* pos_bias = (const float*)d_in[10];
    float* out = (float*)d_out;

    const int M = PB * PN;  // 8192
    char* ws = (char*)d_ws;
    size_t off = 0;
    auto alloc = [&](size_t bytes) -> void* {
        void* p = ws + off;
        off += (bytes + 255) & ~(size_t)255;
        return p;
    };
    __hip_bfloat16* x_bf = (__hip_bfloat16*)alloc((size_t)M * PD * 2);
    __hip_bfloat16* wqkv_bf = (__hip_bfloat16*)alloc((size_t)3 * PD * PD * 2);
    __hip_bfloat16* wgate_bf = (__hip_bfloat16*)alloc((size_t)PD * PD * 2);
    __hip_bfloat16* wout_bf = (__hip_bfloat16*)alloc((size_t)PD * PD * 2);
    float* qkv = (float*)alloc((size_t)M * 3 * PD * 4);
    float* att = (float*)alloc((size_t)M * PD * 4);
    __hip_bfloat16* gated = (__hip_bfloat16*)alloc((size_t)M * PD * 2);

    // casts
    cast_f32_to_bf16<<<(M * PD) / 256, 256, 0, stream>>>(x, x_bf, M * PD);
    cast_f32_to_bf16<<<(3 * PD * PD) / 256, 256, 0, stream>>>(W_qkv, wqkv_bf, 3 * PD * PD);
    cast_f32_to_bf16<<<(PD * PD) / 256, 256, 0, stream>>>(W_gate, wgate_bf, PD * PD);
    cast_f32_to_bf16<<<(PD * PD) / 256, 256, 0, stream>>>(W_out, wout_bf, PD * PD);

    // qkv = x @ W_qkv^T + b_qkv  -> [8192, 3072] fp32
    gemm_bt<0><<<dim3(3 * PD / BN, M / BM), 256, 0, stream>>>(
        x_bf, wqkv_bf, b_qkv, nullptr, qkv, M, 3 * PD, PD);

    // attention -> att [8192, 1024] fp32
    attn_kernel<<<(PB * PH * PN) / 4, 256, 0, stream>>>(
        qkv, scale_gain, W_qscale, identity_bypass, pos_bias, att);

    // gated = bf16(att * sigmoid(x @ W_gate^T + b_gate))
    gemm_bt<1><<<dim3(PD / BN, M / BM), 256, 0, stream>>>(
        x_bf, wgate_bf, b_gate, att, gated, M, PD, PD);

    // out = gated @ W_out^T + b_out  -> fp32
    gemm_bt<0><<<dim3(PD / BN, M / BM), 256, 0, stream>>>(
        gated, wout_bf, b_out, nullptr, out, M, PD, PD);
}

// Round 2
// 439.844 us; speedup vs baseline: 2.3469x; 2.3469x over previous
//
#include <hip/hip_runtime.h>
#include <hip/hip_bf16.h>

// Problem constants
#define PB 4
#define PN 2048
#define PD 1024
#define PH 16
#define PHD 64
#define NSC 11

typedef __attribute__((ext_vector_type(8))) short short8;
typedef __attribute__((ext_vector_type(4))) float floatx4;

// ---------------- cast kernel ----------------
__global__ void cast_f32_to_bf16(const float* __restrict__ in,
                                 __hip_bfloat16* __restrict__ out, int n) {
    int i = blockIdx.x * blockDim.x + threadIdx.x;
    if (i < n) out[i] = __float2bfloat16(in[i]);
}

// ---------------- GEMM: C = A @ B^T (+bias, epilogue) ----------------
// A: [M,K] bf16 row-major; Bm: [Nn,K] bf16 row-major (i.e. W[out][in]).
// EPI 0: out fp32 = acc + bias[col]
// EPI 1: out bf16 = bf16(extra[row,col] * sigmoid(acc + bias[col]))
#define BM 64
#define BN 64
#define BK 32
#define SKP 40  // padded LDS row stride in bf16 elements (80B)

template <int EPI>
__global__ __launch_bounds__(256) void gemm_bt(
    const __hip_bfloat16* __restrict__ A,
    const __hip_bfloat16* __restrict__ Bm,
    const float* __restrict__ bias,
    const float* __restrict__ extra,
    void* __restrict__ outp,
    int M, int Nn, int K) {
    __shared__ alignas(16) __hip_bfloat16 sA[BM * SKP];
    __shared__ alignas(16) __hip_bfloat16 sB[BN * SKP];

    const int tid = threadIdx.x;
    const int lane = tid & 63;
    const int wave = tid >> 6;       // 0..3
    const int wy = wave >> 1;        // 0..1
    const int wx = wave & 1;         // 0..1

    const int ld_row = tid >> 2;         // 0..63
    const int ld_k = (tid & 3) * 8;      // 0,8,16,24

    const int rowA = blockIdx.y * BM + ld_row;
    const int rowB = blockIdx.x * BN + ld_row;

    floatx4 acc[2][2];
#pragma unroll
    for (int i = 0; i < 2; i++)
#pragma unroll
        for (int j = 0; j < 2; j++) acc[i][j] = (floatx4){0.f, 0.f, 0.f, 0.f};

    const int qd = lane >> 4;   // 0..3
    const int r16 = lane & 15;  // 0..15

    for (int k0 = 0; k0 < K; k0 += BK) {
        uint4 va = *(const uint4*)(A + (size_t)rowA * K + k0 + ld_k);
        uint4 vb = *(const uint4*)(Bm + (size_t)rowB * K + k0 + ld_k);
        __syncthreads();
        *(uint4*)(sA + ld_row * SKP + ld_k) = va;
        *(uint4*)(sB + ld_row * SKP + ld_k) = vb;
        __syncthreads();

        short8 af[2], bf[2];
#pragma unroll
        for (int i = 0; i < 2; i++) {
            af[i] = *(const short8*)(sA + (wy * 32 + i * 16 + r16) * SKP + qd * 8);
            bf[i] = *(const short8*)(sB + (wx * 32 + i * 16 + r16) * SKP + qd * 8);
        }
#pragma unroll
        for (int i = 0; i < 2; i++)
#pragma unroll
            for (int j = 0; j < 2; j++)
                acc[i][j] = __builtin_amdgcn_mfma_f32_16x16x32_bf16(
                    af[i], bf[j], acc[i][j], 0, 0, 0);
    }

#pragma unroll
    for (int i = 0; i < 2; i++) {
#pragma unroll
        for (int j = 0; j < 2; j++) {
#pragma unroll
            for (int e = 0; e < 4; e++) {
                int row = blockIdx.y * BM + wy * 32 + i * 16 + qd * 4 + e;
                int col = blockIdx.x * BN + wx * 32 + j * 16 + r16;
                float v = acc[i][j][e] + bias[col];
                if (EPI == 0) {
                    ((float*)outp)[(size_t)row * Nn + col] = v;
                } else {
                    float g = 1.f / (1.f + expf(-v));
                    float a = extra[(size_t)row * Nn + col];
                    ((__hip_bfloat16*)outp)[(size_t)row * Nn + col] =
                        __float2bfloat16(a * g);
                }
            }
        }
    }
}

// ---------------- attention kernel ----------------
// Layout: 1 wave = 4 consecutive n positions; 16 lanes x float4 per position.
// qkv: [B, N, 3D] fp32 (q | k | v chunks of D); att: [B, N, D] fp32.

// 21 distinct nonzero offsets, each serving 1-2 (j,tau) taps.
__device__ __constant__ const int OFFS[21] = {1, 2, 3, 4, 6, 8, 12, 16, 24, 32, 48,
                                              64, 96, 128, 192, 256, 384, 512, 768, 1024, 1536};
__device__ __constant__ const int U1J[21] = {0, 0, 0, 1, 1, 2, 2, 3, 3, 4, 4,
                                             5, 5, 6, 6, 7, 7, 8, 8, 9, 9};
__device__ __constant__ const int U1T[21] = {1, 2, 3, 2, 3, 2, 3, 2, 3, 2, 3,
                                             2, 3, 2, 3, 2, 3, 2, 3, 2, 3};
// second user j (tau is always 1); -1 = none
__device__ __constant__ const int U2J[21] = {-1, 1, -1, 2, -1, 3, -1, 4, -1, 5, -1,
                                             6, -1, 7, -1, 8, -1, 9, -1, 10, -1};

__global__ __launch_bounds__(256) void attn_kernel(
    const float* __restrict__ qkv,
    const float* __restrict__ scale_gain,       // [11,16]
    const float* __restrict__ W_qscale,         // [11,64]
    const float* __restrict__ identity_bypass,  // [16]
    const float* __restrict__ pos_bias,         // [44,16]
    float* __restrict__ att) {
    const int lane = threadIdx.x & 63;
    const int p = lane >> 4;   // position within wave, 0..3
    const int l = lane & 15;   // d-chunk, 0..15

    const int flat = (blockIdx.x * 4 + (threadIdx.x >> 6)) * 4;  // first n of wave
    const int n = (flat & (PN - 1)) + p;
    const int h = (flat >> 11) & (PH - 1);
    const int b = flat >> 15;

    const size_t base_bn = (size_t)b * PN;
    const int col = h * PHD + l * 4;

    const float4 q4 = *(const float4*)(qkv + (base_bn + n) * (3 * PD) + col);
    const float4 k04 = *(const float4*)(qkv + (base_bn + n) * (3 * PD) + PD + col);
    const float4 v04 = *(const float4*)(qkv + (base_bn + n) * (3 * PD) + 2 * PD + col);

    auto dot16 = [](float4 a, float4 b) {
        float s = a.x * b.x;
        s = fmaf(a.y, b.y, s);
        s = fmaf(a.z, b.z, s);
        s = fmaf(a.w, b.w, s);
        s += __shfl_xor(s, 1);
        s += __shfl_xor(s, 2);
        s += __shfl_xor(s, 4);
        s += __shfl_xor(s, 8);
        return s;  // broadcast within the 16-lane group
    };

    const float dot0 = dot16(q4, k04);

    // gains = softmax(q @ W_qscale^T + scale_gain[:,h]) over 11 scales
    float g[NSC];
    float mx = -1e30f;
#pragma unroll
    for (int s = 0; s < NSC; s++) {
        const float4 w4 = *(const float4*)(W_qscale + s * PHD + l * 4);
        g[s] = dot16(q4, w4) + scale_gain[s * PH + h];
        mx = fmaxf(mx, g[s]);
    }
    float ssum = 0.f;
#pragma unroll
    for (int s = 0; s < NSC; s++) {
        g[s] = __expf(g[s] - mx);
        ssum += g[s];
    }
    const float inv = 1.f / ssum;
#pragma unroll
    for (int s = 0; s < NSC; s++) g[s] *= inv;

    const float D4c[4] = {0.4829629131445341f, 0.8365163037378079f,
                          0.2241438680420134f, -0.1294095225512604f};

    float4 out4 = {0.f, 0.f, 0.f, 0.f};
    float z = 0.f;

    // offset-0 taps: tau=0 for every scale j
#pragma unroll
    for (int j = 0; j < NSC; j++) {
        const float xx = dot0 + pos_bias[(j * 4) * PH + h];
        const float feat = (xx > 0.f ? xx : __expf(xx) - 1.f) + 1.f;
        const float w = g[j] * D4c[0] * feat;
        out4.x = fmaf(w, v04.x, out4.x);
        out4.y = fmaf(w, v04.y, out4.y);
        out4.z = fmaf(w, v04.z, out4.z);
        out4.w = fmaf(w, v04.w, out4.w);
        z = fmaf(g[j] * D4c[0], feat, z);  // |coef| == coef for tau=0
    }

    // distinct nonzero offsets (each used by 1-2 taps)
#pragma unroll
    for (int t = 0; t < 21; t++) {
        const int off = OFFS[t];
        const bool valid = (n >= off);
        const int idx = valid ? (n - off) : 0;
        const size_t rb = (base_bn + idx) * (3 * PD);
        float4 k4 = *(const float4*)(qkv + rb + PD + col);
        float4 v4 = *(const float4*)(qkv + rb + 2 * PD + col);
        const float vm = valid ? 1.f : 0.f;
        const float dv = dot16(q4, k4) * vm;
        v4.x *= vm; v4.y *= vm; v4.z *= vm; v4.w *= vm;

        // user 1: (U1J[t], U1T[t])
        {
            const int j = U1J[t], tau = U1T[t];
            const float xx = dv + pos_bias[(j * 4 + tau) * PH + h];
            const float feat = (xx > 0.f ? xx : __expf(xx) - 1.f) + 1.f;
            const float coef = D4c[tau];
            const float w = g[j] * coef * feat;
            out4.x = fmaf(w, v4.x, out4.x);
            out4.y = fmaf(w, v4.y, out4.y);
            out4.z = fmaf(w, v4.z, out4.z);
            out4.w = fmaf(w, v4.w, out4.w);
            z = fmaf(g[j] * fabsf(coef), feat, z);
        }
        // user 2: (U2J[t], tau=1) if present
        if (U2J[t] >= 0) {
            const int j = U2J[t];
            const float xx = dv + pos_bias[(j * 4 + 1) * PH + h];
            const float feat = (xx > 0.f ? xx : __expf(xx) - 1.f) + 1.f;
            const float coef = D4c[1];
            const float w = g[j] * coef * feat;
            out4.x = fmaf(w, v4.x, out4.x);
            out4.y = fmaf(w, v4.y, out4.y);
            out4.z = fmaf(w, v4.z, out4.z);
            out4.w = fmaf(w, v4.w, out4.w);
            z = fmaf(g[j] * fabsf(coef), feat, z);
        }
    }

    // identity bypass
    const float bp = log1pf(__expf(identity_bypass[h]));  // softplus
    const float f0 = (dot0 > 0.f ? dot0 : __expf(dot0) - 1.f) + 1.f;
    const float w0 = bp * f0;
    out4.x = fmaf(w0, v04.x, out4.x);
    out4.y = fmaf(w0, v04.y, out4.y);
    out4.z = fmaf(w0, v04.z, out4.z);
    out4.w = fmaf(w0, v04.w, out4.w);
    z += w0;

    const float zi = 1.f / (z + 1e-6f);
    float4 o;
    o.x = out4.x * zi; o.y = out4.y * zi; o.z = out4.z * zi; o.w = out4.w * zi;
    *(float4*)(att + (base_bn + n) * PD + col) = o;
}

// ---------------- launch ----------------
extern "C" void kernel_launch(void* const* d_in, const int* in_sizes, int n_in,
                              void* d_out, int out_size, void* d_ws, size_t ws_size,
                              hipStream_t stream) {
    const float* x = (const float*)d_in[0];
    const float* W_qkv = (const float*)d_in[1];
    const float* b_qkv = (const float*)d_in[2];
    const float* W_out = (const float*)d_in[3];
    const float* b_out = (const float*)d_in[4];
    const float* W_gate = (const float*)d_in[5];
    const float* b_gate = (const float*)d_in[6];
    const float* scale_gain = (const float*)d_in[7];
    const float* W_qscale = (const float*)d_in[8];
    const float* identity_bypass = (const float*)d_in[9];
    const float* pos_bias = (const float*)d_in[10];
    float* out = (float*)d_out;

    const int M = PB * PN;  // 8192
    char* ws = (char*)d_ws;
    size_t off = 0;
    auto alloc = [&](size_t bytes) -> void* {
        void* p = ws + off;
        off += (bytes + 255) & ~(size_t)255;
        return p;
    };
    __hip_bfloat16* x_bf = (__hip_bfloat16*)alloc((size_t)M * PD * 2);
    __hip_bfloat16* wqkv_bf = (__hip_bfloat16*)alloc((size_t)3 * PD * PD * 2);
    __hip_bfloat16* wgate_bf = (__hip_bfloat16*)alloc((size_t)PD * PD * 2);
    __hip_bfloat16* wout_bf = (__hip_bfloat16*)alloc((size_t)PD * PD * 2);
    float* qkv = (float*)alloc((size_t)M * 3 * PD * 4);
    float* att = (float*)alloc((size_t)M * PD * 4);
    __hip_bfloat16* gated = (__hip_bfloat16*)alloc((size_t)M * PD * 2);

    // casts
    cast_f32_to_bf16<<<(M * PD) / 256, 256, 0, stream>>>(x, x_bf, M * PD);
    cast_f32_to_bf16<<<(3 * PD * PD) / 256, 256, 0, stream>>>(W_qkv, wqkv_bf, 3 * PD * PD);
    cast_f32_to_bf16<<<(PD * PD) / 256, 256, 0, stream>>>(W_gate, wgate_bf, PD * PD);
    cast_f32_to_bf16<<<(PD * PD) / 256, 256, 0, stream>>>(W_out, wout_bf, PD * PD);

    // qkv = x @ W_qkv^T + b_qkv  -> [8192, 3072] fp32
    gemm_bt<0><<<dim3(3 * PD / BN, M / BM), 256, 0, stream>>>(
        x_bf, wqkv_bf, b_qkv, nullptr, qkv, M, 3 * PD, PD);

    // attention -> att [8192, 1024] fp32
    attn_kernel<<<(PB * PH * PN) / 16, 256, 0, stream>>>(
        qkv, scale_gain, W_qscale, identity_bypass, pos_bias, att);

    // gated = bf16(att * sigmoid(x @ W_gate^T + b_gate))
    gemm_bt<1><<<dim3(PD / BN, M / BM), 256, 0, stream>>>(
        x_bf, wgate_bf, b_gate, att, gated, M, PD, PD);

    // out = gated @ W_out^T + b_out  -> fp32
    gemm_bt<0><<<dim3(PD / BN, M / BM), 256, 0, stream>>>(
        gated, wout_bf, b_out, nullptr, out, M, PD, PD);
}

// Round 4
// 367.934 us; speedup vs baseline: 2.8056x; 1.1954x over previous
//
#include <hip/hip_runtime.h>
#include <hip/hip_bf16.h>

// Problem constants
#define PB 4
#define PN 2048
#define PD 1024
#define PH 16
#define PHD 64
#define NSC 11

typedef __attribute__((ext_vector_type(8))) short short8;
typedef __attribute__((ext_vector_type(4))) float floatx4;

#define AS1 __attribute__((address_space(1)))
#define AS3 __attribute__((address_space(3)))

static __device__ __forceinline__ unsigned short bf16bits(float f) {
    __hip_bfloat16 h = __float2bfloat16(f);
    return __builtin_bit_cast(unsigned short, h);
}

// ---------------- cast kernel (4 elems/thread) ----------------
__global__ void cast_f32_to_bf16_v4(const float4* __restrict__ in,
                                    ushort4* __restrict__ out, int n4) {
    int i = blockIdx.x * blockDim.x + threadIdx.x;
    if (i < n4) {
        float4 v = in[i];
        ushort4 o;
        o.x = bf16bits(v.x);
        o.y = bf16bits(v.y);
        o.z = bf16bits(v.z);
        o.w = bf16bits(v.w);
        out[i] = o;
    }
}

// ---------------- GEMM 128x128: C = A @ B^T (+bias, epilogue) ----------------
// A: [M,K] bf16 row-major; Bm: [Nn,K] bf16 row-major (W[out][in]).
// EPI 0: out fp32 = acc + bias[col]
// EPI 1: out bf16 = bf16(extra[row,col] * sigmoid(acc + bias[col]))
// m97 structure: global_load_lds width-16 staging, unpadded LDS (row stride
// 32 bf16 = 64 B -> 2-way bank alias, measured free), 4x4 MFMA acc per wave.
#define GBM 128
#define GBN 128
#define GBK 32

template <int EPI>
__global__ __launch_bounds__(256) void gemm_bt128(
    const __hip_bfloat16* __restrict__ A,
    const __hip_bfloat16* __restrict__ Bm,
    const float* __restrict__ bias,
    const float* __restrict__ extra,
    void* __restrict__ outp,
    int Nn, int K) {
    __shared__ alignas(16) __hip_bfloat16 sA[GBM * GBK];
    __shared__ alignas(16) __hip_bfloat16 sB[GBN * GBK];

    const int tid = threadIdx.x;
    const int lane = tid & 63;
    const int wave = tid >> 6;   // 0..3
    const int wy = wave >> 1;    // 0..1
    const int wx = wave & 1;     // 0..1

    // staging map: lane i of a wave-call covers row base+i/4, k-chunk (i%4)*8
    const int lrow = lane >> 2;      // 0..15
    const int lk = (lane & 3) * 8;   // 0,8,16,24

    const int r16 = lane & 15;
    const int qd = lane >> 4;

    floatx4 acc[4][4];
#pragma unroll
    for (int i = 0; i < 4; i++)
#pragma unroll
        for (int j = 0; j < 4; j++) acc[i][j] = (floatx4){0.f, 0.f, 0.f, 0.f};

    const size_t arow0 = (size_t)blockIdx.y * GBM;
    const size_t brow0 = (size_t)blockIdx.x * GBN;

    for (int k0 = 0; k0 < K; k0 += GBK) {
        __syncthreads();  // previous ds_reads done before overwrite
#pragma unroll
        for (int half = 0; half < 2; half++) {
            const int rbase = wave * 16 + half * 64;  // wave-uniform
            const __hip_bfloat16* gA = A + (arow0 + rbase + lrow) * K + k0 + lk;
            __builtin_amdgcn_global_load_lds(
                (const AS1 unsigned int*)(const void*)gA,
                (AS3 unsigned int*)(void*)(sA + rbase * GBK), 16, 0, 0);
            const __hip_bfloat16* gB = Bm + (brow0 + rbase + lrow) * K + k0 + lk;
            __builtin_amdgcn_global_load_lds(
                (const AS1 unsigned int*)(const void*)gB,
                (AS3 unsigned int*)(void*)(sB + rbase * GBK), 16, 0, 0);
        }
        __syncthreads();  // drain staging

        short8 af[4], bf[4];
#pragma unroll
        for (int i = 0; i < 4; i++)
            af[i] = *(const short8*)(sA + (wy * 64 + i * 16 + r16) * GBK + qd * 8);
#pragma unroll
        for (int j = 0; j < 4; j++)
            bf[j] = *(const short8*)(sB + (wx * 64 + j * 16 + r16) * GBK + qd * 8);
#pragma unroll
        for (int i = 0; i < 4; i++)
#pragma unroll
            for (int j = 0; j < 4; j++)
                acc[i][j] = __builtin_amdgcn_mfma_f32_16x16x32_bf16(
                    af[i], bf[j], acc[i][j], 0, 0, 0);
    }

#pragma unroll
    for (int i = 0; i < 4; i++) {
#pragma unroll
        for (int j = 0; j < 4; j++) {
#pragma unroll
            for (int e = 0; e < 4; e++) {
                const size_t row = arow0 + wy * 64 + i * 16 + qd * 4 + e;
                const size_t col = brow0 + wx * 64 + j * 16 + r16;
                float v = acc[i][j][e] + bias[col];
                if (EPI == 0) {
                    ((float*)outp)[row * Nn + col] = v;
                } else {
                    float g = 1.f / (1.f + __expf(-v));
                    float a = extra[row * Nn + col];
                    ((__hip_bfloat16*)outp)[row * Nn + col] = __float2bfloat16(a * g);
                }
            }
        }
    }
}

// ---------------- attention kernel ----------------
// Layout: 1 wave = 4 consecutive n positions; 16 lanes x float4 per position.
// qkv: [B, N, 3D] fp32 (q | k | v chunks of D); att: [B, N, D] fp32.

// 21 distinct nonzero offsets, each serving 1-2 (j,tau) taps.
__device__ __constant__ const int OFFS[21] = {1, 2, 3, 4, 6, 8, 12, 16, 24, 32, 48,
                                              64, 96, 128, 192, 256, 384, 512, 768, 1024, 1536};
__device__ __constant__ const int U1J[21] = {0, 0, 0, 1, 1, 2, 2, 3, 3, 4, 4,
                                             5, 5, 6, 6, 7, 7, 8, 8, 9, 9};
__device__ __constant__ const int U1T[21] = {1, 2, 3, 2, 3, 2, 3, 2, 3, 2, 3,
                                             2, 3, 2, 3, 2, 3, 2, 3, 2, 3};
// second user j (tau is always 1); -1 = none
__device__ __constant__ const int U2J[21] = {-1, 1, -1, 2, -1, 3, -1, 4, -1, 5, -1,
                                             6, -1, 7, -1, 8, -1, 9, -1, 10, -1};

__global__ __launch_bounds__(256) void attn_kernel(
    const float* __restrict__ qkv,
    const float* __restrict__ scale_gain,       // [11,16]
    const float* __restrict__ W_qscale,         // [11,64]
    const float* __restrict__ identity_bypass,  // [16]
    const float* __restrict__ pos_bias,         // [44,16]
    float* __restrict__ att) {
    const int lane = threadIdx.x & 63;
    const int p = lane >> 4;   // position within wave, 0..3
    const int l = lane & 15;   // d-chunk, 0..15

    const int flat = (blockIdx.x * 4 + (threadIdx.x >> 6)) * 4;  // first n of wave
    const int n = (flat & (PN - 1)) + p;
    const int h = (flat >> 11) & (PH - 1);
    const int b = flat >> 15;

    const size_t base_bn = (size_t)b * PN;
    const int col = h * PHD + l * 4;

    const float4 q4 = *(const float4*)(qkv + (base_bn + n) * (3 * PD) + col);
    const float4 k04 = *(const float4*)(qkv + (base_bn + n) * (3 * PD) + PD + col);
    const float4 v04 = *(const float4*)(qkv + (base_bn + n) * (3 * PD) + 2 * PD + col);

    auto dot16 = [](float4 a, float4 b) {
        float s = a.x * b.x;
        s = fmaf(a.y, b.y, s);
        s = fmaf(a.z, b.z, s);
        s = fmaf(a.w, b.w, s);
        s += __shfl_xor(s, 1);
        s += __shfl_xor(s, 2);
        s += __shfl_xor(s, 4);
        s += __shfl_xor(s, 8);
        return s;  // broadcast within the 16-lane group
    };

    const float dot0 = dot16(q4, k04);

    // gains = softmax(q @ W_qscale^T + scale_gain[:,h]) over 11 scales
    float g[NSC];
    float mx = -1e30f;
#pragma unroll
    for (int s = 0; s < NSC; s++) {
        const float4 w4 = *(const float4*)(W_qscale + s * PHD + l * 4);
        g[s] = dot16(q4, w4) + scale_gain[s * PH + h];
        mx = fmaxf(mx, g[s]);
    }
    float ssum = 0.f;
#pragma unroll
    for (int s = 0; s < NSC; s++) {
        g[s] = __expf(g[s] - mx);
        ssum += g[s];
    }
    const float inv = 1.f / ssum;
#pragma unroll
    for (int s = 0; s < NSC; s++) g[s] *= inv;

    const float D4c[4] = {0.4829629131445341f, 0.8365163037378079f,
                          0.2241438680420134f, -0.1294095225512604f};

    float4 out4 = {0.f, 0.f, 0.f, 0.f};
    float z = 0.f;

    // offset-0 taps: tau=0 for every scale j
#pragma unroll
    for (int j = 0; j < NSC; j++) {
        const float xx = dot0 + pos_bias[(j * 4) * PH + h];
        const float feat = (xx > 0.f ? xx : __expf(xx) - 1.f) + 1.f;
        const float w = g[j] * D4c[0] * feat;
        out4.x = fmaf(w, v04.x, out4.x);
        out4.y = fmaf(w, v04.y, out4.y);
        out4.z = fmaf(w, v04.z, out4.z);
        out4.w = fmaf(w, v04.w, out4.w);
        z = fmaf(g[j] * D4c[0], feat, z);  // |coef| == coef for tau=0
    }

    // distinct nonzero offsets (each used by 1-2 taps)
#pragma unroll
    for (int t = 0; t < 21; t++) {
        const int off = OFFS[t];
        const bool valid = (n >= off);
        const int idx = valid ? (n - off) : 0;
        const size_t rb = (base_bn + idx) * (3 * PD);
        float4 k4 = *(const float4*)(qkv + rb + PD + col);
        float4 v4 = *(const float4*)(qkv + rb + 2 * PD + col);
        const float vm = valid ? 1.f : 0.f;
        const float dv = dot16(q4, k4) * vm;
        v4.x *= vm; v4.y *= vm; v4.z *= vm; v4.w *= vm;

        // user 1: (U1J[t], U1T[t])
        {
            const int j = U1J[t], tau = U1T[t];
            const float xx = dv + pos_bias[(j * 4 + tau) * PH + h];
            const float feat = (xx > 0.f ? xx : __expf(xx) - 1.f) + 1.f;
            const float coef = D4c[tau];
            const float w = g[j] * coef * feat;
            out4.x = fmaf(w, v4.x, out4.x);
            out4.y = fmaf(w, v4.y, out4.y);
            out4.z = fmaf(w, v4.z, out4.z);
            out4.w = fmaf(w, v4.w, out4.w);
            z = fmaf(g[j] * fabsf(coef), feat, z);
        }
        // user 2: (U2J[t], tau=1) if present
        if (U2J[t] >= 0) {
            const int j = U2J[t];
            const float xx = dv + pos_bias[(j * 4 + 1) * PH + h];
            const float feat = (xx > 0.f ? xx : __expf(xx) - 1.f) + 1.f;
            const float coef = D4c[1];
            const float w = g[j] * coef * feat;
            out4.x = fmaf(w, v4.x, out4.x);
            out4.y = fmaf(w, v4.y, out4.y);
            out4.z = fmaf(w, v4.z, out4.z);
            out4.w = fmaf(w, v4.w, out4.w);
            z = fmaf(g[j] * fabsf(coef), feat, z);
        }
    }

    // identity bypass
    const float bp = log1pf(__expf(identity_bypass[h]));  // softplus
    const float f0 = (dot0 > 0.f ? dot0 : __expf(dot0) - 1.f) + 1.f;
    const float w0 = bp * f0;
    out4.x = fmaf(w0, v04.x, out4.x);
    out4.y = fmaf(w0, v04.y, out4.y);
    out4.z = fmaf(w0, v04.z, out4.z);
    out4.w = fmaf(w0, v04.w, out4.w);
    z += w0;

    const float zi = 1.f / (z + 1e-6f);
    float4 o;
    o.x = out4.x * zi; o.y = out4.y * zi; o.z = out4.z * zi; o.w = out4.w * zi;
    *(float4*)(att + (base_bn + n) * PD + col) = o;
}

// ---------------- launch ----------------
extern "C" void kernel_launch(void* const* d_in, const int* in_sizes, int n_in,
                              void* d_out, int out_size, void* d_ws, size_t ws_size,
                              hipStream_t stream) {
    const float* x = (const float*)d_in[0];
    const float* W_qkv = (const float*)d_in[1];
    const float* b_qkv = (const float*)d_in[2];
    const float* W_out = (const float*)d_in[3];
    const float* b_out = (const float*)d_in[4];
    const float* W_gate = (const float*)d_in[5];
    const float* b_gate = (const float*)d_in[6];
    const float* scale_gain = (const float*)d_in[7];
    const float* W_qscale = (const float*)d_in[8];
    const float* identity_bypass = (const float*)d_in[9];
    const float* pos_bias = (const float*)d_in[10];
    float* out = (float*)d_out;

    const int M = PB * PN;  // 8192
    char* ws = (char*)d_ws;
    size_t off = 0;
    auto alloc = [&](size_t bytes) -> void* {
        void* p = ws + off;
        off += (bytes + 255) & ~(size_t)255;
        return p;
    };
    __hip_bfloat16* x_bf = (__hip_bfloat16*)alloc((size_t)M * PD * 2);
    __hip_bfloat16* wqkv_bf = (__hip_bfloat16*)alloc((size_t)3 * PD * PD * 2);
    __hip_bfloat16* wgate_bf = (__hip_bfloat16*)alloc((size_t)PD * PD * 2);
    __hip_bfloat16* wout_bf = (__hip_bfloat16*)alloc((size_t)PD * PD * 2);
    float* qkv = (float*)alloc((size_t)M * 3 * PD * 4);
    float* att = (float*)alloc((size_t)M * PD * 4);
    __hip_bfloat16* gated = (__hip_bfloat16*)alloc((size_t)M * PD * 2);

    // casts (4 elems/thread)
    cast_f32_to_bf16_v4<<<(M * PD / 4) / 256, 256, 0, stream>>>(
        (const float4*)x, (ushort4*)x_bf, M * PD / 4);
    cast_f32_to_bf16_v4<<<(3 * PD * PD / 4) / 256, 256, 0, stream>>>(
        (const float4*)W_qkv, (ushort4*)wqkv_bf, 3 * PD * PD / 4);
    cast_f32_to_bf16_v4<<<(PD * PD / 4) / 256, 256, 0, stream>>>(
        (const float4*)W_gate, (ushort4*)wgate_bf, PD * PD / 4);
    cast_f32_to_bf16_v4<<<(PD * PD / 4) / 256, 256, 0, stream>>>(
        (const float4*)W_out, (ushort4*)wout_bf, PD * PD / 4);

    // qkv = x @ W_qkv^T + b_qkv  -> [8192, 3072] fp32
    gemm_bt128<0><<<dim3(3 * PD / GBN, M / GBM), 256, 0, stream>>>(
        x_bf, wqkv_bf, b_qkv, nullptr, qkv, 3 * PD, PD);

    // attention -> att [8192, 1024] fp32
    attn_kernel<<<(PB * PH * PN) / 16, 256, 0, stream>>>(
        qkv, scale_gain, W_qscale, identity_bypass, pos_bias, att);

    // gated = bf16(att * sigmoid(x @ W_gate^T + b_gate))
    gemm_bt128<1><<<dim3(PD / GBN, M / GBM), 256, 0, stream>>>(
        x_bf, wgate_bf, b_gate, att, gated, PD, PD);

    // out = gated @ W_out^T + b_out  -> fp32
    gemm_bt128<0><<<dim3(PD / GBN, M / GBM), 256, 0, stream>>>(
        gated, wout_bf, b_out, nullptr, out, PD, PD);
}